// Round 21
// baseline (206.309 us; speedup 1.0000x reference)
//
#include <hip/hip_runtime.h>
#include <hip/hip_bf16.h>
#include <math.h>

#define B_   8
#define NH_  8
#define D_   96
#define C_   768
#define N_   1569          // 8*14*14 + 1
#define NKV_ 393           // 8*7*7 + 1
#define M_   (B_*N_)       // 12552
#define QKV1 ((size_t)B_*NH_*N_*D_)    // 9,639,936 elems per tensor
#define QPAD 1664          // padded q rows per slab (13 tiles of 128)
#define KPAD 416           // padded kv rows per slab (13 tiles of 32)
#define SCALE_ 0.10206207261596575f    // 96^-0.5

using short8v = __attribute__((ext_vector_type(8))) short;
using f32x4   = __attribute__((ext_vector_type(4))) float;
using f32x2   = __attribute__((ext_vector_type(2))) float;
typedef unsigned short u16;

// HW-verified form only: offset immediate = 0 (nonzero offset semantics are
// NOT verified on gfx950 and broke correctness in round 19/20).
#define GLOAD_LDS16(g, l) __builtin_amdgcn_global_load_lds( \
    (const __attribute__((address_space(1))) void*)(g),     \
    (__attribute__((address_space(3))) void*)(l), 16, 0, 0)

static __device__ __forceinline__ u16 f2bf(float f) {
    __hip_bfloat16 b = __float2bfloat16(f);
    return *(u16*)&b;
}

// bijective XCD swizzle (m204): consecutive swizzled ids land on one XCD
static __device__ __forceinline__ unsigned xcd_swizzle(unsigned orig, unsigned nwg) {
    const unsigned qq = nwg >> 3, rr = nwg & 7;
    const unsigned xcd = orig & 7, loc = orig >> 3;
    return (xcd < rr ? xcd * (qq + 1) : rr * (qq + 1) + (xcd - rr) * qq) + loc;
}

// ---------------------------------------------------------------------------
// Merged prep kernel: block-range dispatch over 5 jobs.
// ---------------------------------------------------------------------------
#define PREP_CVT_B   9414
#define PREP_WQ_B    1728
#define PREP_WP_B    576
#define PREP_WT_B    31
#define PREP_ZP_B    552
#define PREP_BLOCKS  (PREP_CVT_B + PREP_WQ_B + PREP_WP_B + PREP_WT_B + PREP_ZP_B)

static __device__ __forceinline__
void tile_transpose(const float* __restrict__ W, u16* __restrict__ Wt,
                    int ncols, int n0, int k0, float* tile /*[32][33]*/)
{
    const int tx = threadIdx.x & 31, ty = threadIdx.x >> 5;   // 32 x 8
    #pragma unroll
    for (int i = 0; i < 4; ++i)
        tile[(ty + i * 8) * 33 + tx] = W[(size_t)(k0 + ty + i * 8) * ncols + n0 + tx];
    __syncthreads();
    #pragma unroll
    for (int i = 0; i < 4; ++i)
        Wt[(size_t)(n0 + ty + i * 8) * 768 + k0 + tx] = f2bf(tile[tx * 33 + ty + i * 8]);
}

__global__ __launch_bounds__(256)
void prep_kernel(const float* __restrict__ x, const float* __restrict__ Wqkv,
                 const float* __restrict__ Wproj,
                 const float* __restrict__ cwq, const float* __restrict__ cwk,
                 const float* __restrict__ cwv,
                 u16* __restrict__ x16, u16* __restrict__ Wqkvt,
                 u16* __restrict__ Wprojt, float* __restrict__ cwT,
                 u16* __restrict__ vt16)
{
    __shared__ float tile[32 * 33];
    const int bid = blockIdx.x;
    const int tid = threadIdx.x;

    if (bid < PREP_CVT_B) {
        const int i = bid * 256 + tid;
        const int n4 = M_ * 768 / 4;
        if (i < n4) {
            const float4 v = ((const float4*)x)[i];
            ushort4 o;
            o.x = f2bf(v.x); o.y = f2bf(v.y); o.z = f2bf(v.z); o.w = f2bf(v.w);
            ((ushort4*)x16)[i] = o;
        }
    } else if (bid < PREP_CVT_B + PREP_WQ_B) {
        const int b2 = bid - PREP_CVT_B;
        tile_transpose(Wqkv, Wqkvt, 2304, (b2 % 72) * 32, (b2 / 72) * 32, tile);
    } else if (bid < PREP_CVT_B + PREP_WQ_B + PREP_WP_B) {
        const int b2 = bid - PREP_CVT_B - PREP_WQ_B;
        tile_transpose(Wproj, Wprojt, 768, (b2 % 24) * 32, (b2 / 24) * 32, tile);
    } else if (bid < PREP_CVT_B + PREP_WQ_B + PREP_WP_B + PREP_WT_B) {
        const int i = (bid - PREP_CVT_B - PREP_WQ_B - PREP_WP_B) * 256 + tid;
        if (i < 3 * 27 * 96) {
            const int tsr = i / 2592;
            const int r = i - tsr * 2592;
            const int tap = r / 96, ch = r - tap * 96;
            const float* src = tsr == 0 ? cwq : (tsr == 1 ? cwk : cwv);
            cwT[i] = src[ch * 27 + tap];
        }
    } else {
        const int i = (bid - PREP_CVT_B - PREP_WQ_B - PREP_WP_B - PREP_WT_B) * 256 + tid;
        const int total = 64 * 96 * (KPAD - NKV_);
        if (i < total) {
            const int j = i % (KPAD - NKV_);
            const int rest = i / (KPAD - NKV_);     // slab*96 + d
            vt16[(size_t)rest * KPAD + NKV_ + j] = 0;
        }
    }
}

// ---------------------------------------------------------------------------
// bf16 MFMA GEMM v5: round-18 structure + pointer-bump staging (verified
// offset=0 loads; per-stage cost = 6 pointer adds instead of full addr calc).
// ---------------------------------------------------------------------------
template<int NC, int BN, bool SCATTER>
__global__ __launch_bounds__(512, 4)
void gemm_bf16_kernel(const u16* __restrict__ A, const u16* __restrict__ Bt,
                      const float* __restrict__ bias, void* __restrict__ outp)
{
    constexpr int NXT    = NC / BN;
    constexpr int WN     = BN / 4;        // wave n-width: 64 or 32
    constexpr int NBF    = WN / 16;       // b-frags per kk: 4 or 2
    constexpr int BLOADS = BN / 64;       // B stage loads/thread: 4 or 2

    __shared__ alignas(16) u16 As[128 * 64];
    __shared__ alignas(16) u16 Bs[BN * 64];

    const int tid  = threadIdx.x;
    const int w    = tid >> 6, lane = tid & 63;
    const int c    = lane & 15, g = lane >> 4;
    const int wm   = w >> 2, wn = w & 3;      // 2m x 4n wave grid
    const int lrow = lane >> 3, lcol = lane & 7;

    const unsigned wg = xcd_swizzle(blockIdx.x, gridDim.x);
    const int m0 = (int)(wg / NXT) * 128;
    const int n0 = (int)(wg % NXT) * BN;

    // precomputed stage source pointers (bumped by 64 elems per K-step)
    const u16* asrc[2];
    int adst[2];
    #pragma unroll
    for (int it2 = 0; it2 < 2; ++it2) {
        const int rb = it2 * 64 + w * 8;
        const int row = rb + lrow;
        const int scol = (lcol ^ (row & 7)) * 8;
        int m = m0 + row; if (m >= M_) m = M_ - 1;
        asrc[it2] = A + (size_t)m * 768 + scol;
        adst[it2] = rb * 64;
    }
    const u16* bsrc[BLOADS];
    int bdst[BLOADS];
    #pragma unroll
    for (int it2 = 0; it2 < BLOADS; ++it2) {
        const int rb = it2 * 64 + w * 8;
        const int row = rb + lrow;
        const int scol = (lcol ^ (row & 7)) * 8;
        bsrc[it2] = Bt + (size_t)(n0 + row) * 768 + scol;
        bdst[it2] = rb * 64;
    }

    f32x4 acc[4][NBF];
    #pragma unroll
    for (int i = 0; i < 4; ++i)
        #pragma unroll
        for (int j = 0; j < NBF; ++j) acc[i][j] = (f32x4){0.f, 0.f, 0.f, 0.f};

#define STAGE() do {                                                             \
    _Pragma("unroll")                                                            \
    for (int it2 = 0; it2 < 2; ++it2) {                                          \
        GLOAD_LDS16(asrc[it2], &As[adst[it2]]);                                  \
        asrc[it2] += 64;                                                         \
    }                                                                            \
    _Pragma("unroll")                                                            \
    for (int it2 = 0; it2 < BLOADS; ++it2) {                                     \
        GLOAD_LDS16(bsrc[it2], &Bs[bdst[it2]]);                                  \
        bsrc[it2] += 64;                                                         \
    } } while (0)

    const int xora = (g ^ (c & 7)) * 8;          // kk=0: logical col16 = g
    const int xorb = ((4 + g) ^ (c & 7)) * 8;    // kk=1: logical col16 = 4+g

#define KSTEP(PREF) do {                                                         \
    asm volatile("s_waitcnt vmcnt(0)" ::: "memory");                             \
    __builtin_amdgcn_s_barrier();                                                \
    {                                                                            \
        short8v a0[4], b0[NBF];                                                  \
        _Pragma("unroll")                                                        \
        for (int i = 0; i < 4; ++i)                                              \
            a0[i] = *(const short8v*)&As[(wm * 64 + i * 16 + c) * 64 + xora];    \
        _Pragma("unroll")                                                        \
        for (int j = 0; j < NBF; ++j)                                            \
            b0[j] = *(const short8v*)&Bs[(wn * WN + j * 16 + c) * 64 + xora];    \
        asm volatile("s_waitcnt lgkmcnt(0)" ::: "memory");                       \
        __builtin_amdgcn_sched_barrier(0);                                       \
        __builtin_amdgcn_s_setprio(1);                                           \
        _Pragma("unroll")                                                        \
        for (int i = 0; i < 4; ++i)                                              \
            _Pragma("unroll")                                                    \
            for (int j = 0; j < NBF; ++j)                                        \
                acc[i][j] = __builtin_amdgcn_mfma_f32_16x16x32_bf16(             \
                    a0[i], b0[j], acc[i][j], 0, 0, 0);                           \
        __builtin_amdgcn_s_setprio(0);                                           \
    }                                                                            \
    {                                                                            \
        short8v a1[4], b1[NBF];                                                  \
        _Pragma("unroll")                                                        \
        for (int i = 0; i < 4; ++i)                                              \
            a1[i] = *(const short8v*)&As[(wm * 64 + i * 16 + c) * 64 + xorb];    \
        _Pragma("unroll")                                                        \
        for (int j = 0; j < NBF; ++j)                                            \
            b1[j] = *(const short8v*)&Bs[(wn * WN + j * 16 + c) * 64 + xorb];    \
        asm volatile("s_waitcnt lgkmcnt(0)" ::: "memory");                       \
        __builtin_amdgcn_sched_barrier(0);                                       \
        __builtin_amdgcn_s_barrier();                                            \
        if (PREF) STAGE();                                                       \
        __builtin_amdgcn_s_setprio(1);                                           \
        _Pragma("unroll")                                                        \
        for (int i = 0; i < 4; ++i)                                              \
            _Pragma("unroll")                                                    \
            for (int j = 0; j < NBF; ++j)                                        \
                acc[i][j] = __builtin_amdgcn_mfma_f32_16x16x32_bf16(             \
                    a1[i], b1[j], acc[i][j], 0, 0, 0);                           \
        __builtin_amdgcn_s_setprio(0);                                           \
    } } while (0)

    STAGE();
    #pragma unroll
    for (int t = 0; t < 12; ++t) KSTEP(t + 1 < 12);
#undef STAGE
#undef KSTEP

    #pragma unroll
    for (int i = 0; i < 4; ++i) {
        const int mrow = m0 + wm * 64 + i * 16 + g * 4;
        #pragma unroll
        for (int j = 0; j < NBF; ++j) {
            const int ncol = n0 + wn * WN + j * 16 + c;
            const float bv = bias[ncol];
            if constexpr (SCATTER) {
                u16* out = (u16*)outp;
                const int s   = ncol / C_;          // 0=q,1=k,2=v
                const int rem = ncol - s * C_;
                const int hh  = rem / D_;
                const int dd  = rem - hh * D_;
                #pragma unroll
                for (int r = 0; r < 4; ++r) {
                    const int m = mrow + r;
                    if (m < M_) {
                        const int bb2 = m / N_;
                        const int n = m - bb2 * N_;
                        out[(size_t)s * QKV1 +
                            ((size_t)(bb2 * NH_ + hh) * N_ + n) * D_ + dd] = f2bf(acc[i][j][r] + bv);
                    }
                }
            } else {
                float* out = (float*)outp;
                #pragma unroll
                for (int r = 0; r < 4; ++r) {
                    const int m = mrow + r;
                    if (m < M_) out[(size_t)m * NC + ncol] = acc[i][j][r] + bv;
                }
            }
        }
    }
}

// ---------------------------------------------------------------------------
// Pool+LN v5: 16-lane groups, 6 channels/lane, no LDS, direct global reads.
// ---------------------------------------------------------------------------
static __device__ __forceinline__ void loadx6(const u16* __restrict__ rowp,
                                              int iw, f32x2 x[3])
{
    if (iw < 0 || iw >= 14) {      // compile-time after unroll
        x[0] = x[1] = x[2] = (f32x2){0.f, 0.f};
        return;
    }
    const unsigned* p = (const unsigned*)(rowp + (size_t)iw * 96);
    #pragma unroll
    for (int j = 0; j < 3; ++j) {
        const unsigned u = p[j];
        x[j][0] = __uint_as_float(u << 16);
        x[j][1] = __uint_as_float(u & 0xffff0000u);
    }
}

template<int STRIDE, int OHW, int WMODE, int WO0>
static __device__ __forceinline__
void pool_task(const u16* __restrict__ in, const float* __restrict__ cwT,
               const float* __restrict__ g, const float* __restrict__ bta,
               u16* __restrict__ out, int tokstride, int bh, int to, int ho,
               float oscale)
{
    const int sl = threadIdx.x & 15;
    const u16* base = in + (size_t)bh * N_ * 96 + 6 * sl;

    f32x2 acc[7][3];
    #pragma unroll
    for (int i = 0; i < 7; ++i)
        #pragma unroll
        for (int p = 0; p < 3; ++p) acc[i][p] = (f32x2){0.f, 0.f};

    #pragma unroll
    for (int dt = 0; dt < 3; ++dt) {
        const int t = to - 1 + dt;
        if (t < 0 || t > 7) continue;
        #pragma unroll
        for (int dh = 0; dh < 3; ++dh) {
            const int h = ho * STRIDE - 1 + dh;
            if (h < 0 || h >= 14) continue;
            const int tapb = dt * 9 + dh * 3;
            f32x2 wt[3][3];
            #pragma unroll
            for (int dw = 0; dw < 3; ++dw)
                #pragma unroll
                for (int p = 0; p < 3; ++p)
                    wt[dw][p] = *(const f32x2*)&cwT[(tapb + dw) * 96 + 6 * sl + 2 * p];
            const u16* rowp = base + (size_t)(1 + t * 196 + h * 14) * 96;

            if constexpr (STRIDE == 1) {
                f32x2 xm[3], x0[3], xp[3];
                loadx6(rowp, WO0 - 1, xm);
                loadx6(rowp, WO0, x0);
                #pragma unroll
                for (int wo = 0; wo < 7; ++wo) {
                    loadx6(rowp, WO0 + wo + 1, xp);
                    #pragma unroll
                    for (int p = 0; p < 3; ++p) {
                        acc[wo][p] = __builtin_elementwise_fma(wt[0][p], xm[p], acc[wo][p]);
                        acc[wo][p] = __builtin_elementwise_fma(wt[1][p], x0[p], acc[wo][p]);
                        acc[wo][p] = __builtin_elementwise_fma(wt[2][p], xp[p], acc[wo][p]);
                        xm[p] = x0[p]; x0[p] = xp[p];
                    }
                }
            } else {
                #pragma unroll
                for (int wo = 0; wo < 7; ++wo) {
                    #pragma unroll
                    for (int dw = 0; dw < 3; ++dw) {
                        f32x2 xa[3];
                        loadx6(rowp, 2 * wo - 1 + dw, xa);
                        #pragma unroll
                        for (int p = 0; p < 3; ++p)
                            acc[wo][p] = __builtin_elementwise_fma(wt[dw][p], xa[p], acc[wo][p]);
                    }
                }
            }
        }
    }

    f32x2 gg[3], bb[3];
    #pragma unroll
    for (int p = 0; p < 3; ++p) {
        gg[p] = *(const f32x2*)&g[6 * sl + 2 * p] * oscale;
        bb[p] = *(const f32x2*)&bta[6 * sl + 2 * p] * oscale;
    }

    #pragma unroll
    for (int wo = 0; wo < 7; ++wo) {
        float s = acc[wo][0][0] + acc[wo][0][1] + acc[wo][1][0] + acc[wo][1][1]
                + acc[wo][2][0] + acc[wo][2][1];
        float sq = acc[wo][0][0] * acc[wo][0][0];
        sq = fmaf(acc[wo][0][1], acc[wo][0][1], sq);
        sq = fmaf(acc[wo][1][0], acc[wo][1][0], sq);
        sq = fmaf(acc[wo][1][1], acc[wo][1][1], sq);
        sq = fmaf(acc[wo][2][0], acc[wo][2][0], sq);
        sq = fmaf(acc[wo][2][1], acc[wo][2][1], sq);
        #pragma unroll
        for (int off = 1; off < 16; off <<= 1) {
            s  += __shfl_xor(s, off, 64);
            sq += __shfl_xor(sq, off, 64);
        }
        const float mu = s * (1.f / 96.f);
        const float rstd = rsqrtf(sq * (1.f / 96.f) - mu * mu + 1e-5f);
        const f32x2 muv = (f32x2){mu, mu};
        const int tok = 1 + (to * OHW + ho) * OHW + WO0 + wo;
        u16 yb[6];
        #pragma unroll
        for (int p = 0; p < 3; ++p) {
            const f32x2 y = (acc[wo][p] - muv) * rstd * gg[p] + bb[p];
            yb[2 * p] = f2bf(y[0]); yb[2 * p + 1] = f2bf(y[1]);
        }
        if constexpr (WMODE == 2) {
            #pragma unroll
            for (int j = 0; j < 6; ++j)
                out[((size_t)bh * 96 + 6 * sl + j) * KPAD + tok] = yb[j];
        } else {
            unsigned* op = (unsigned*)&out[((size_t)bh * tokstride + tok) * 96 + 6 * sl];
            #pragma unroll
            for (int p = 0; p < 3; ++p)
                op[p] = (unsigned)yb[2 * p] | ((unsigned)yb[2 * p + 1] << 16);
        }
    }
}

template<int WMODE>
static __device__ __forceinline__
void pool_cls_v5(const u16* __restrict__ in, const float* __restrict__ g,
                 const float* __restrict__ bta, u16* __restrict__ out,
                 int tokstride, int bh, float oscale)
{
    const int sl = threadIdx.x & 15;
    const unsigned* p = (const unsigned*)(in + (size_t)bh * N_ * 96 + 6 * sl);
    f32x2 v[3];
    #pragma unroll
    for (int j = 0; j < 3; ++j) {
        const unsigned u = p[j];
        v[j][0] = __uint_as_float(u << 16);
        v[j][1] = __uint_as_float(u & 0xffff0000u);
    }
    float s = v[0][0] + v[0][1] + v[1][0] + v[1][1] + v[2][0] + v[2][1];
    float sq = v[0][0]*v[0][0] + v[0][1]*v[0][1] + v[1][0]*v[1][0]
             + v[1][1]*v[1][1] + v[2][0]*v[2][0] + v[2][1]*v[2][1];
    #pragma unroll
    for (int off = 1; off < 16; off <<= 1) {
        s  += __shfl_xor(s, off, 64);
        sq += __shfl_xor(sq, off, 64);
    }
    const float mu = s * (1.f / 96.f);
    const float rstd = rsqrtf(sq * (1.f / 96.f) - mu * mu + 1e-5f);
    u16 yb[6];
    #pragma unroll
    for (int p2 = 0; p2 < 3; ++p2) {
        const f32x2 gg = *(const f32x2*)&g[6 * sl + 2 * p2] * oscale;
        const f32x2 bb = *(const f32x2*)&bta[6 * sl + 2 * p2] * oscale;
        const f32x2 y = (v[p2] - (f32x2){mu, mu}) * rstd * gg + bb;
        yb[2 * p2] = f2bf(y[0]); yb[2 * p2 + 1] = f2bf(y[1]);
    }
    if constexpr (WMODE == 2) {
        #pragma unroll
        for (int j = 0; j < 6; ++j)
            out[((size_t)bh * 96 + 6 * sl + j) * KPAD] = yb[j];
    } else {
        unsigned* op = (unsigned*)&out[(size_t)bh * tokstride * 96 + 6 * sl];
        #pragma unroll
        for (int p2 = 0; p2 < 3; ++p2)
            op[p2] = (unsigned)yb[2 * p2] | ((unsigned)yb[2 * p2 + 1] << 16);
    }
}

// task ids: q chunk0 [0,7168), q chunk1 [7168,14336), k [14336,17920),
// v [17920,21504), cls [21504,21696)
#define NTASKS 21696
__global__ __launch_bounds__(256)
void pool_ln_v5_kernel(const u16* __restrict__ qin, const u16* __restrict__ kin,
                       const u16* __restrict__ vin, const float* __restrict__ cwT,
                       const float* __restrict__ gq, const float* __restrict__ bq,
                       const float* __restrict__ gk, const float* __restrict__ bk,
                       const float* __restrict__ gv, const float* __restrict__ bv,
                       u16* __restrict__ qout, u16* __restrict__ kout,
                       u16* __restrict__ vtout)
{
    const unsigned wg = xcd_swizzle(blockIdx.x, gridDim.x);
    const int gid = (int)(wg * 16 + (threadIdx.x >> 4));
    if (gid >= NTASKS) return;

    if (gid < 14336) {                       // q
        const int chunk = gid / 7168;
        const int r = gid - chunk * 7168;
        const int ho = r % 14;
        const int to = (r / 14) & 7;
        const int bh = r / 112;
        if (chunk == 0)
            pool_task<1, 14, 0, 0>(qin, cwT, gq, bq, qout, QPAD, bh, to, ho, SCALE_);
        else
            pool_task<1, 14, 0, 7>(qin, cwT, gq, bq, qout, QPAD, bh, to, ho, SCALE_);
    } else if (gid < 17920) {                // k
        const int r = gid - 14336;
        const int ho = r % 7;
        const int to = (r / 7) & 7;
        const int bh = r / 56;
        pool_task<2, 7, 0, 0>(kin, cwT + 2592, gk, bk, kout, KPAD, bh, to, ho, 1.f);
    } else if (gid < 21504) {                // v (transposed out)
        const int r = gid - 17920;
        const int ho = r % 7;
        const int to = (r / 7) & 7;
        const int bh = r / 56;
        pool_task<2, 7, 2, 0>(vin, cwT + 5184, gv, bv, vtout, KPAD, bh, to, ho, 1.f);
    } else {                                 // cls
        const int r = gid - 21504;
        const int tsr = r >> 6, bh = r & 63;
        if (tsr == 0)      pool_cls_v5<0>(qin, gq, bq, qout, QPAD, bh, SCALE_);
        else if (tsr == 1) pool_cls_v5<0>(kin, gk, bk, kout, KPAD, bh, 1.f);
        else               pool_cls_v5<2>(vin, gv, bv, vtout, KPAD, bh, 1.f);
    }
}

// ---------------------------------------------------------------------------
// MFMA attention v3 -> bf16 [M_][768]. 32 q-rows/wave, K reg double-buffer,
// VT hoisted; per-subtile exp/PV interleave (PV0 MFMA overlaps exp1 VALU).
// ---------------------------------------------------------------------------
__global__ __launch_bounds__(256)
void attn_mfma_kernel(const u16* __restrict__ Q, const u16* __restrict__ K,
                      const u16* __restrict__ VT, u16* __restrict__ Out)
{
    __shared__ alignas(16) u16 plds[4][2][512];   // per-wave, per-subtile P tile
    const int tid  = threadIdx.x;
    const int w    = tid >> 6, lane = tid & 63;
    const int c    = lane & 15, g = lane >> 4;

    const unsigned wg = xcd_swizzle(blockIdx.x, gridDim.x);
    const int bh = (int)(wg / 13);
    const int b  = bh >> 3, hh = bh & 7;
    const int q0 = (int)(wg % 13) * 128 + w * 32;

    const size_t qbase = (size_t)bh * QPAD * 96;
    const size_t kbase = (size_t)bh * KPAD * 96;

    short8v qa[2][3];
    #pragma unroll
    for (int s2 = 0; s2 < 2; ++s2)
        #pragma unroll
        for (int kf = 0; kf < 3; ++kf)
            qa[s2][kf] = *(const short8v*)
                &Q[qbase + (size_t)(q0 + s2 * 16 + c) * 96 + kf * 32 + g * 8];

    f32x4 oacc[2][6];
    #pragma unroll
    for (int s2 = 0; s2 < 2; ++s2)
        #pragma unroll
        for (int t = 0; t < 6; ++t) oacc[s2][t] = (f32x4){0.f, 0.f, 0.f, 0.f};
    float lsum[2][4] = {{0.f,0.f,0.f,0.f},{0.f,0.f,0.f,0.f}};

    short8v kb[2][6];
#define LOADK(IDX, PR) do {                                                     \
    _Pragma("unroll")                                                           \
    for (int h = 0; h < 2; ++h)                                                 \
        _Pragma("unroll")                                                       \
        for (int kf = 0; kf < 3; ++kf)                                          \
            kb[IDX][h * 3 + kf] = *(const short8v*)                             \
                &K[kbase + (size_t)((PR) * 32 + h * 16 + c) * 96 + kf * 32 + g * 8]; \
    } while (0)

    LOADK(0, 0);

    #pragma unroll
    for (int pr = 0; pr < 13; ++pr) {
        const int cur = pr & 1, nxt = cur ^ 1;

        short8v vt[6];
        #pragma unroll
        for (int t = 0; t < 6; ++t)
            vt[t] = *(const short8v*)
                &VT[kbase + (size_t)(t * 16 + c) * KPAD + pr * 32 + g * 8];

        f32x4 sacc[2][2];
        __builtin_amdgcn_s_setprio(1);
        #pragma unroll
        for (int s2 = 0; s2 < 2; ++s2)
            #pragma unroll
            for (int h = 0; h < 2; ++h) {
                f32x4 sa = (f32x4){0.f, 0.f, 0.f, 0.f};
                sa = __builtin_amdgcn_mfma_f32_16x16x32_bf16(qa[s2][0], kb[cur][h*3+0], sa, 0, 0, 0);
                sa = __builtin_amdgcn_mfma_f32_16x16x32_bf16(qa[s2][1], kb[cur][h*3+1], sa, 0, 0, 0);
                sa = __builtin_amdgcn_mfma_f32_16x16x32_bf16(qa[s2][2], kb[cur][h*3+2], sa, 0, 0, 0);
                sacc[s2][h] = sa;
            }
        __builtin_amdgcn_s_setprio(0);

        if (pr < 12) LOADK(nxt, pr + 1);

        // subtile 0: exp -> LDS -> PV0 (its MFMA overlaps subtile 1's exp VALU)
        #pragma unroll
        for (int h = 0; h < 2; ++h) {
            const int jcol = pr * 32 + h * 16 + c;
            #pragma unroll
            for (int r = 0; r < 4; ++r) {
                float s = sacc[0][h][r];
                if (jcol >= NKV_) s = -1e30f;
                const float p = __expf(s);
                lsum[0][r] += p;
                const int q    = g * 4 + r;
                const int j    = h * 16 + c;
                const int dstL = q | ((j >> 3) << 4);
                plds[w][0][dstL * 8 + (j & 7)] = f2bf(p);
            }
        }
        asm volatile("s_waitcnt lgkmcnt(0)" ::: "memory");
        __builtin_amdgcn_sched_barrier(0);
        {
            const short8v pa0 = *(const short8v*)&plds[w][0][lane * 8];
            __builtin_amdgcn_s_setprio(1);
            #pragma unroll
            for (int t = 0; t < 6; ++t)
                oacc[0][t] = __builtin_amdgcn_mfma_f32_16x16x32_bf16(pa0, vt[t], oacc[0][t], 0, 0, 0);
            __builtin_amdgcn_s_setprio(0);
        }

        // subtile 1
        #pragma unroll
        for (int h = 0; h < 2; ++h) {
            const int jcol = pr * 32 + h * 16 + c;
            #pragma unroll
            for (int r = 0; r < 4; ++r) {
                float s = sacc[1][h][r];
                if (jcol >= NKV_) s = -1e30f;
                const float p = __expf(s);
                lsum[1][r] += p;
                const int q    = g * 4 + r;
                const int j    = h * 16 + c;
                const int dstL = q | ((j >> 3) << 4);
                plds[w][1][dstL * 8 + (j & 7)] = f2bf(p);
            }
        }
        asm volatile("s_waitcnt lgkmcnt(0)" ::: "memory");
        __builtin_amdgcn_sched_barrier(0);
        {
            const short8v pa1 = *(const short8v*)&plds[w][1][lane * 8];
            __builtin_amdgcn_s_setprio(1);
            #pragma unroll
            for (int t = 0; t < 6; ++t)
                oacc[1][t] = __builtin_amdgcn_mfma_f32_16x16x32_bf16(pa1, vt[t], oacc[1][t], 0, 0, 0);
            __builtin_amdgcn_s_setprio(0);
        }
    }
#undef LOADK

    float linv[2][4];
    #pragma unroll
    for (int s2 = 0; s2 < 2; ++s2)
        #pragma unroll
        for (int r = 0; r < 4; ++r) {
            float s = lsum[s2][r];
            s += __shfl_xor(s, 1, 64);
            s += __shfl_xor(s, 2, 64);
            s += __shfl_xor(s, 4, 64);
            s += __shfl_xor(s, 8, 64);
            linv[s2][r] = 1.f / s;
        }

    #pragma unroll
    for (int s2 = 0; s2 < 2; ++s2)
        #pragma unroll
        for (int t = 0; t < 6; ++t)
            #pragma unroll
            for (int r = 0; r < 4; ++r) {
                const int row = q0 + s2 * 16 + g * 4 + r;
                if (row < N_)
                    Out[((size_t)(b * N_ + row)) * 768 + hh * 96 + t * 16 + c] =
                        f2bf(oacc[s2][t][r] * linv[s2][r]);
            }
}

// ---------------------------------------------------------------------------
extern "C" void kernel_launch(void* const* d_in, const int* in_sizes, int n_in,
                              void* d_out, int out_size, void* d_ws, size_t ws_size,
                              hipStream_t stream)
{
    const float* x     = (const float*)d_in[0];
    const float* Wqkv  = (const float*)d_in[1];
    const float* bqkv  = (const float*)d_in[2];
    const float* Wproj = (const float*)d_in[3];
    const float* bproj = (const float*)d_in[4];
    const float* cwq   = (const float*)d_in[5];
    const float* cwk   = (const float*)d_in[6];
    const float* cwv   = (const float*)d_in[7];
    const float* lnqg  = (const float*)d_in[8];
    const float* lnqb  = (const float*)d_in[9];
    const float* lnkg  = (const float*)d_in[10];
    const float* lnkb  = (const float*)d_in[11];
    const float* lnvg  = (const float*)d_in[12];
    const float* lnvb  = (const float*)d_in[13];

    u16* ws = (u16*)d_ws;
    u16* qkv_raw = ws;                       // 3 x [B][NH][N][D] bf16
    u16* q16 = qkv_raw + 3 * QKV1;           // [64][QPAD][96]
    u16* k16 = q16 + (size_t)64 * QPAD * 96; // [64][KPAD][96]
    u16* vt16 = k16 + (size_t)64 * KPAD * 96;// [64][96][KPAD] (transposed)
    u16* x16    = vt16 + (size_t)64 * KPAD * 96;  // [12552][768]
    u16* Wqkvt  = x16 + (size_t)M_ * 768;         // [2304][768]
    u16* Wprojt = Wqkvt + (size_t)2304 * 768;     // [768][768]
    float* cwT  = (float*)(Wprojt + (size_t)768 * 768);  // 3 x [27][96] f32
    u16* attn16 = qkv_raw;                   // alias: raw dead after pooling
    float* out = (float*)d_out;

    // 0) merged prep: cvt x, transpose weights, transpose conv w, vt pad
    prep_kernel<<<PREP_BLOCKS, 256, 0, stream>>>(
        x, Wqkv, Wproj, cwq, cwk, cwv, x16, Wqkvt, Wprojt, cwT, vt16);

    // 1) qkv GEMM (128x256) with bf16 scatter into q/k/v
    gemm_bf16_kernel<2304, 256, true><<<99 * 9, 512, 0, stream>>>(x16, Wqkvt, bqkv, qkv_raw);

    // 2) pool + LN v5: 16-lane groups, no LDS, task-per-group
    pool_ln_v5_kernel<<<(NTASKS + 15) / 16, 256, 0, stream>>>(
        qkv_raw, qkv_raw + QKV1, qkv_raw + 2 * QKV1, cwT,
        lnqg, lnqb, lnkg, lnkb, lnvg, lnvb, q16, k16, vt16);

    // 3) MFMA attention v3 -> bf16 [M_][768]
    attn_mfma_kernel<<<13 * 64, 256, 0, stream>>>(q16, k16, vt16, attn16);

    // 4) output projection (128x128 -> 594 blocks) -> fp32 d_out
    gemm_bf16_kernel<768, 128, false><<<99 * 6, 512, 0, stream>>>(attn16, Wprojt, bproj, out);
}

// Round 22
// 187.282 us; speedup vs baseline: 1.1016x; 1.1016x over previous
//
#include <hip/hip_runtime.h>
#include <hip/hip_bf16.h>
#include <math.h>

#define B_   8
#define NH_  8
#define D_   96
#define C_   768
#define N_   1569          // 8*14*14 + 1
#define NKV_ 393           // 8*7*7 + 1
#define M_   (B_*N_)       // 12552
#define QKV1 ((size_t)B_*NH_*N_*D_)    // 9,639,936 elems per tensor
#define QPAD 1664          // padded q rows per slab (13 tiles of 128)
#define KPAD 416           // padded kv rows per slab (13 tiles of 32)
#define SCALE_ 0.10206207261596575f    // 96^-0.5

using short8v = __attribute__((ext_vector_type(8))) short;
using f32x4   = __attribute__((ext_vector_type(4))) float;
using f32x2   = __attribute__((ext_vector_type(2))) float;
typedef unsigned short u16;

#define GLOAD_LDS16(g, l) __builtin_amdgcn_global_load_lds( \
    (const __attribute__((address_space(1))) void*)(g),     \
    (__attribute__((address_space(3))) void*)(l), 16, 0, 0)

static __device__ __forceinline__ u16 f2bf(float f) {
    __hip_bfloat16 b = __float2bfloat16(f);
    return *(u16*)&b;
}

// bijective XCD swizzle (m204): consecutive swizzled ids land on one XCD
static __device__ __forceinline__ unsigned xcd_swizzle(unsigned orig, unsigned nwg) {
    const unsigned qq = nwg >> 3, rr = nwg & 7;
    const unsigned xcd = orig & 7, loc = orig >> 3;
    return (xcd < rr ? xcd * (qq + 1) : rr * (qq + 1) + (xcd - rr) * qq) + loc;
}

// ---------------------------------------------------------------------------
// Merged prep kernel: block-range dispatch over 5 jobs.
// ---------------------------------------------------------------------------
#define PREP_CVT_B   9414
#define PREP_WQ_B    1728
#define PREP_WP_B    576
#define PREP_WT_B    31
#define PREP_ZP_B    552
#define PREP_BLOCKS  (PREP_CVT_B + PREP_WQ_B + PREP_WP_B + PREP_WT_B + PREP_ZP_B)

static __device__ __forceinline__
void tile_transpose(const float* __restrict__ W, u16* __restrict__ Wt,
                    int ncols, int n0, int k0, float* tile /*[32][33]*/)
{
    const int tx = threadIdx.x & 31, ty = threadIdx.x >> 5;   // 32 x 8
    #pragma unroll
    for (int i = 0; i < 4; ++i)
        tile[(ty + i * 8) * 33 + tx] = W[(size_t)(k0 + ty + i * 8) * ncols + n0 + tx];
    __syncthreads();
    #pragma unroll
    for (int i = 0; i < 4; ++i)
        Wt[(size_t)(n0 + ty + i * 8) * 768 + k0 + tx] = f2bf(tile[tx * 33 + ty + i * 8]);
}

__global__ __launch_bounds__(256)
void prep_kernel(const float* __restrict__ x, const float* __restrict__ Wqkv,
                 const float* __restrict__ Wproj,
                 const float* __restrict__ cwq, const float* __restrict__ cwk,
                 const float* __restrict__ cwv,
                 u16* __restrict__ x16, u16* __restrict__ Wqkvt,
                 u16* __restrict__ Wprojt, float* __restrict__ cwT,
                 u16* __restrict__ vt16)
{
    __shared__ float tile[32 * 33];
    const int bid = blockIdx.x;
    const int tid = threadIdx.x;

    if (bid < PREP_CVT_B) {
        const int i = bid * 256 + tid;
        const int n4 = M_ * 768 / 4;
        if (i < n4) {
            const float4 v = ((const float4*)x)[i];
            ushort4 o;
            o.x = f2bf(v.x); o.y = f2bf(v.y); o.z = f2bf(v.z); o.w = f2bf(v.w);
            ((ushort4*)x16)[i] = o;
        }
    } else if (bid < PREP_CVT_B + PREP_WQ_B) {
        const int b2 = bid - PREP_CVT_B;
        tile_transpose(Wqkv, Wqkvt, 2304, (b2 % 72) * 32, (b2 / 72) * 32, tile);
    } else if (bid < PREP_CVT_B + PREP_WQ_B + PREP_WP_B) {
        const int b2 = bid - PREP_CVT_B - PREP_WQ_B;
        tile_transpose(Wproj, Wprojt, 768, (b2 % 24) * 32, (b2 / 24) * 32, tile);
    } else if (bid < PREP_CVT_B + PREP_WQ_B + PREP_WP_B + PREP_WT_B) {
        const int i = (bid - PREP_CVT_B - PREP_WQ_B - PREP_WP_B) * 256 + tid;
        if (i < 3 * 27 * 96) {
            const int tsr = i / 2592;
            const int r = i - tsr * 2592;
            const int tap = r / 96, ch = r - tap * 96;
            const float* src = tsr == 0 ? cwq : (tsr == 1 ? cwk : cwv);
            cwT[i] = src[ch * 27 + tap];
        }
    } else {
        const int i = (bid - PREP_CVT_B - PREP_WQ_B - PREP_WP_B - PREP_WT_B) * 256 + tid;
        const int total = 64 * 96 * (KPAD - NKV_);
        if (i < total) {
            const int j = i % (KPAD - NKV_);
            const int rest = i / (KPAD - NKV_);     // slab*96 + d
            vt16[(size_t)rest * KPAD + NKV_ + j] = 0;
        }
    }
}

// ---------------------------------------------------------------------------
// bf16 MFMA GEMM (round-18 verified config): BM=128, BN in {256,128}, BK=64;
// 8 waves (2m x 4n), wave tile 64 x (BN/4). Single-buffered LDS.
// Per K-step: vmcnt(0)+bar -> {a0,b0 frags -> MFMA kk0} -> {a1,b1 frags ->
// bar -> STAGE(t+1) -> MFMA kk1}. Address recompute per stage (register-cheap;
// pointer-bump and offset-immediate variants both regressed: spills / wrong
// semantics on gfx950).
// ---------------------------------------------------------------------------
template<int NC, int BN, bool SCATTER>
__global__ __launch_bounds__(512, 4)
void gemm_bf16_kernel(const u16* __restrict__ A, const u16* __restrict__ Bt,
                      const float* __restrict__ bias, void* __restrict__ outp)
{
    constexpr int NXT    = NC / BN;
    constexpr int WN     = BN / 4;        // wave n-width: 64 or 32
    constexpr int NBF    = WN / 16;       // b-frags per kk: 4 or 2
    constexpr int BLOADS = BN / 64;       // B stage loads/thread: 4 or 2

    __shared__ alignas(16) u16 As[128 * 64];
    __shared__ alignas(16) u16 Bs[BN * 64];

    const int tid  = threadIdx.x;
    const int w    = tid >> 6, lane = tid & 63;
    const int c    = lane & 15, g = lane >> 4;
    const int wm   = w >> 2, wn = w & 3;      // 2m x 4n wave grid
    const int lrow = lane >> 3, lcol = lane & 7;

    const unsigned wg = xcd_swizzle(blockIdx.x, gridDim.x);
    const int m0 = (int)(wg / NXT) * 128;
    const int n0 = (int)(wg % NXT) * BN;

    f32x4 acc[4][NBF];
    #pragma unroll
    for (int i = 0; i < 4; ++i)
        #pragma unroll
        for (int j = 0; j < NBF; ++j) acc[i][j] = (f32x4){0.f, 0.f, 0.f, 0.f};

#define STAGE(K0) do {                                                           \
    _Pragma("unroll")                                                            \
    for (int it2 = 0; it2 < 2; ++it2) {                                          \
        const int rb = it2 * 64 + w * 8;                                         \
        const int row = rb + lrow;                                               \
        const int scol = (lcol ^ (row & 7)) * 8;                                 \
        int m = m0 + row; if (m >= M_) m = M_ - 1;                               \
        GLOAD_LDS16(&A[(size_t)m * 768 + (K0) + scol], &As[rb * 64]);            \
    }                                                                            \
    _Pragma("unroll")                                                            \
    for (int it2 = 0; it2 < BLOADS; ++it2) {                                     \
        const int rb = it2 * 64 + w * 8;                                         \
        const int row = rb + lrow;                                               \
        const int scol = (lcol ^ (row & 7)) * 8;                                 \
        GLOAD_LDS16(&Bt[(size_t)(n0 + row) * 768 + (K0) + scol], &Bs[rb * 64]);  \
    } } while (0)

    const int xora = (g ^ (c & 7)) * 8;          // kk=0: logical col16 = g
    const int xorb = ((4 + g) ^ (c & 7)) * 8;    // kk=1: logical col16 = 4+g

#define KSTEP(T) do {                                                            \
    asm volatile("s_waitcnt vmcnt(0)" ::: "memory");                             \
    __builtin_amdgcn_s_barrier();                                                \
    {                                                                            \
        short8v a0[4], b0[NBF];                                                  \
        _Pragma("unroll")                                                        \
        for (int i = 0; i < 4; ++i)                                              \
            a0[i] = *(const short8v*)&As[(wm * 64 + i * 16 + c) * 64 + xora];    \
        _Pragma("unroll")                                                        \
        for (int j = 0; j < NBF; ++j)                                            \
            b0[j] = *(const short8v*)&Bs[(wn * WN + j * 16 + c) * 64 + xora];    \
        asm volatile("s_waitcnt lgkmcnt(0)" ::: "memory");                       \
        __builtin_amdgcn_sched_barrier(0);                                       \
        __builtin_amdgcn_s_setprio(1);                                           \
        _Pragma("unroll")                                                        \
        for (int i = 0; i < 4; ++i)                                              \
            _Pragma("unroll")                                                    \
            for (int j = 0; j < NBF; ++j)                                        \
                acc[i][j] = __builtin_amdgcn_mfma_f32_16x16x32_bf16(             \
                    a0[i], b0[j], acc[i][j], 0, 0, 0);                           \
        __builtin_amdgcn_s_setprio(0);                                           \
    }                                                                            \
    {                                                                            \
        short8v a1[4], b1[NBF];                                                  \
        _Pragma("unroll")                                                        \
        for (int i = 0; i < 4; ++i)                                              \
            a1[i] = *(const short8v*)&As[(wm * 64 + i * 16 + c) * 64 + xorb];    \
        _Pragma("unroll")                                                        \
        for (int j = 0; j < NBF; ++j)                                            \
            b1[j] = *(const short8v*)&Bs[(wn * WN + j * 16 + c) * 64 + xorb];    \
        asm volatile("s_waitcnt lgkmcnt(0)" ::: "memory");                       \
        __builtin_amdgcn_sched_barrier(0);                                       \
        __builtin_amdgcn_s_barrier();                                            \
        if ((T) + 1 < 12) STAGE(((T) + 1) * 64);                                 \
        __builtin_amdgcn_s_setprio(1);                                           \
        _Pragma("unroll")                                                        \
        for (int i = 0; i < 4; ++i)                                              \
            _Pragma("unroll")                                                    \
            for (int j = 0; j < NBF; ++j)                                        \
                acc[i][j] = __builtin_amdgcn_mfma_f32_16x16x32_bf16(             \
                    a1[i], b1[j], acc[i][j], 0, 0, 0);                           \
        __builtin_amdgcn_s_setprio(0);                                           \
    } } while (0)

    STAGE(0);
    #pragma unroll
    for (int t = 0; t < 12; ++t) KSTEP(t);
#undef STAGE
#undef KSTEP

    #pragma unroll
    for (int i = 0; i < 4; ++i) {
        const int mrow = m0 + wm * 64 + i * 16 + g * 4;
        #pragma unroll
        for (int j = 0; j < NBF; ++j) {
            const int ncol = n0 + wn * WN + j * 16 + c;
            const float bv = bias[ncol];
            if constexpr (SCATTER) {
                u16* out = (u16*)outp;
                const int s   = ncol / C_;          // 0=q,1=k,2=v
                const int rem = ncol - s * C_;
                const int hh  = rem / D_;
                const int dd  = rem - hh * D_;
                #pragma unroll
                for (int r = 0; r < 4; ++r) {
                    const int m = mrow + r;
                    if (m < M_) {
                        const int bb2 = m / N_;
                        const int n = m - bb2 * N_;
                        out[(size_t)s * QKV1 +
                            ((size_t)(bb2 * NH_ + hh) * N_ + n) * D_ + dd] = f2bf(acc[i][j][r] + bv);
                    }
                }
            } else {
                float* out = (float*)outp;
                #pragma unroll
                for (int r = 0; r < 4; ++r) {
                    const int m = mrow + r;
                    if (m < M_) out[(size_t)m * NC + ncol] = acc[i][j][r] + bv;
                }
            }
        }
    }
}

// ---------------------------------------------------------------------------
// Pool+LN v5: 16-lane groups, 6 channels/lane, no LDS, direct global reads.
// ---------------------------------------------------------------------------
static __device__ __forceinline__ void loadx6(const u16* __restrict__ rowp,
                                              int iw, f32x2 x[3])
{
    if (iw < 0 || iw >= 14) {      // compile-time after unroll
        x[0] = x[1] = x[2] = (f32x2){0.f, 0.f};
        return;
    }
    const unsigned* p = (const unsigned*)(rowp + (size_t)iw * 96);
    #pragma unroll
    for (int j = 0; j < 3; ++j) {
        const unsigned u = p[j];
        x[j][0] = __uint_as_float(u << 16);
        x[j][1] = __uint_as_float(u & 0xffff0000u);
    }
}

template<int STRIDE, int OHW, int WMODE, int WO0>
static __device__ __forceinline__
void pool_task(const u16* __restrict__ in, const float* __restrict__ cwT,
               const float* __restrict__ g, const float* __restrict__ bta,
               u16* __restrict__ out, int tokstride, int bh, int to, int ho,
               float oscale)
{
    const int sl = threadIdx.x & 15;
    const u16* base = in + (size_t)bh * N_ * 96 + 6 * sl;

    f32x2 acc[7][3];
    #pragma unroll
    for (int i = 0; i < 7; ++i)
        #pragma unroll
        for (int p = 0; p < 3; ++p) acc[i][p] = (f32x2){0.f, 0.f};

    #pragma unroll
    for (int dt = 0; dt < 3; ++dt) {
        const int t = to - 1 + dt;
        if (t < 0 || t > 7) continue;
        #pragma unroll
        for (int dh = 0; dh < 3; ++dh) {
            const int h = ho * STRIDE - 1 + dh;
            if (h < 0 || h >= 14) continue;
            const int tapb = dt * 9 + dh * 3;
            f32x2 wt[3][3];
            #pragma unroll
            for (int dw = 0; dw < 3; ++dw)
                #pragma unroll
                for (int p = 0; p < 3; ++p)
                    wt[dw][p] = *(const f32x2*)&cwT[(tapb + dw) * 96 + 6 * sl + 2 * p];
            const u16* rowp = base + (size_t)(1 + t * 196 + h * 14) * 96;

            if constexpr (STRIDE == 1) {
                f32x2 xm[3], x0[3], xp[3];
                loadx6(rowp, WO0 - 1, xm);
                loadx6(rowp, WO0, x0);
                #pragma unroll
                for (int wo = 0; wo < 7; ++wo) {
                    loadx6(rowp, WO0 + wo + 1, xp);
                    #pragma unroll
                    for (int p = 0; p < 3; ++p) {
                        acc[wo][p] = __builtin_elementwise_fma(wt[0][p], xm[p], acc[wo][p]);
                        acc[wo][p] = __builtin_elementwise_fma(wt[1][p], x0[p], acc[wo][p]);
                        acc[wo][p] = __builtin_elementwise_fma(wt[2][p], xp[p], acc[wo][p]);
                        xm[p] = x0[p]; x0[p] = xp[p];
                    }
                }
            } else {
                #pragma unroll
                for (int wo = 0; wo < 7; ++wo) {
                    #pragma unroll
                    for (int dw = 0; dw < 3; ++dw) {
                        f32x2 xa[3];
                        loadx6(rowp, 2 * wo - 1 + dw, xa);
                        #pragma unroll
                        for (int p = 0; p < 3; ++p)
                            acc[wo][p] = __builtin_elementwise_fma(wt[dw][p], xa[p], acc[wo][p]);
                    }
                }
            }
        }
    }

    f32x2 gg[3], bb[3];
    #pragma unroll
    for (int p = 0; p < 3; ++p) {
        gg[p] = *(const f32x2*)&g[6 * sl + 2 * p] * oscale;
        bb[p] = *(const f32x2*)&bta[6 * sl + 2 * p] * oscale;
    }

    #pragma unroll
    for (int wo = 0; wo < 7; ++wo) {
        float s = acc[wo][0][0] + acc[wo][0][1] + acc[wo][1][0] + acc[wo][1][1]
                + acc[wo][2][0] + acc[wo][2][1];
        float sq = acc[wo][0][0] * acc[wo][0][0];
        sq = fmaf(acc[wo][0][1], acc[wo][0][1], sq);
        sq = fmaf(acc[wo][1][0], acc[wo][1][0], sq);
        sq = fmaf(acc[wo][1][1], acc[wo][1][1], sq);
        sq = fmaf(acc[wo][2][0], acc[wo][2][0], sq);
        sq = fmaf(acc[wo][2][1], acc[wo][2][1], sq);
        #pragma unroll
        for (int off = 1; off < 16; off <<= 1) {
            s  += __shfl_xor(s, off, 64);
            sq += __shfl_xor(sq, off, 64);
        }
        const float mu = s * (1.f / 96.f);
        const float rstd = rsqrtf(sq * (1.f / 96.f) - mu * mu + 1e-5f);
        const f32x2 muv = (f32x2){mu, mu};
        const int tok = 1 + (to * OHW + ho) * OHW + WO0 + wo;
        u16 yb[6];
        #pragma unroll
        for (int p = 0; p < 3; ++p) {
            const f32x2 y = (acc[wo][p] - muv) * rstd * gg[p] + bb[p];
            yb[2 * p] = f2bf(y[0]); yb[2 * p + 1] = f2bf(y[1]);
        }
        if constexpr (WMODE == 2) {
            #pragma unroll
            for (int j = 0; j < 6; ++j)
                out[((size_t)bh * 96 + 6 * sl + j) * KPAD + tok] = yb[j];
        } else {
            unsigned* op = (unsigned*)&out[((size_t)bh * tokstride + tok) * 96 + 6 * sl];
            #pragma unroll
            for (int p = 0; p < 3; ++p)
                op[p] = (unsigned)yb[2 * p] | ((unsigned)yb[2 * p + 1] << 16);
        }
    }
}

template<int WMODE>
static __device__ __forceinline__
void pool_cls_v5(const u16* __restrict__ in, const float* __restrict__ g,
                 const float* __restrict__ bta, u16* __restrict__ out,
                 int tokstride, int bh, float oscale)
{
    const int sl = threadIdx.x & 15;
    const unsigned* p = (const unsigned*)(in + (size_t)bh * N_ * 96 + 6 * sl);
    f32x2 v[3];
    #pragma unroll
    for (int j = 0; j < 3; ++j) {
        const unsigned u = p[j];
        v[j][0] = __uint_as_float(u << 16);
        v[j][1] = __uint_as_float(u & 0xffff0000u);
    }
    float s = v[0][0] + v[0][1] + v[1][0] + v[1][1] + v[2][0] + v[2][1];
    float sq = v[0][0]*v[0][0] + v[0][1]*v[0][1] + v[1][0]*v[1][0]
             + v[1][1]*v[1][1] + v[2][0]*v[2][0] + v[2][1]*v[2][1];
    #pragma unroll
    for (int off = 1; off < 16; off <<= 1) {
        s  += __shfl_xor(s, off, 64);
        sq += __shfl_xor(sq, off, 64);
    }
    const float mu = s * (1.f / 96.f);
    const float rstd = rsqrtf(sq * (1.f / 96.f) - mu * mu + 1e-5f);
    u16 yb[6];
    #pragma unroll
    for (int p2 = 0; p2 < 3; ++p2) {
        const f32x2 gg = *(const f32x2*)&g[6 * sl + 2 * p2] * oscale;
        const f32x2 bb = *(const f32x2*)&bta[6 * sl + 2 * p2] * oscale;
        const f32x2 y = (v[p2] - (f32x2){mu, mu}) * rstd * gg + bb;
        yb[2 * p2] = f2bf(y[0]); yb[2 * p2 + 1] = f2bf(y[1]);
    }
    if constexpr (WMODE == 2) {
        #pragma unroll
        for (int j = 0; j < 6; ++j)
            out[((size_t)bh * 96 + 6 * sl + j) * KPAD] = yb[j];
    } else {
        unsigned* op = (unsigned*)&out[(size_t)bh * tokstride * 96 + 6 * sl];
        #pragma unroll
        for (int p2 = 0; p2 < 3; ++p2)
            op[p2] = (unsigned)yb[2 * p2] | ((unsigned)yb[2 * p2 + 1] << 16);
    }
}

// task ids: q chunk0 [0,7168), q chunk1 [7168,14336), k [14336,17920),
// v [17920,21504), cls [21504,21696)
#define NTASKS 21696
__global__ __launch_bounds__(256)
void pool_ln_v5_kernel(const u16* __restrict__ qin, const u16* __restrict__ kin,
                       const u16* __restrict__ vin, const float* __restrict__ cwT,
                       const float* __restrict__ gq, const float* __restrict__ bq,
                       const float* __restrict__ gk, const float* __restrict__ bk,
                       const float* __restrict__ gv, const float* __restrict__ bv,
                       u16* __restrict__ qout, u16* __restrict__ kout,
                       u16* __restrict__ vtout)
{
    const unsigned wg = xcd_swizzle(blockIdx.x, gridDim.x);
    const int gid = (int)(wg * 16 + (threadIdx.x >> 4));
    if (gid >= NTASKS) return;

    if (gid < 14336) {                       // q
        const int chunk = gid / 7168;
        const int r = gid - chunk * 7168;
        const int ho = r % 14;
        const int to = (r / 14) & 7;
        const int bh = r / 112;
        if (chunk == 0)
            pool_task<1, 14, 0, 0>(qin, cwT, gq, bq, qout, QPAD, bh, to, ho, SCALE_);
        else
            pool_task<1, 14, 0, 7>(qin, cwT, gq, bq, qout, QPAD, bh, to, ho, SCALE_);
    } else if (gid < 17920) {                // k
        const int r = gid - 14336;
        const int ho = r % 7;
        const int to = (r / 7) & 7;
        const int bh = r / 56;
        pool_task<2, 7, 0, 0>(kin, cwT + 2592, gk, bk, kout, KPAD, bh, to, ho, 1.f);
    } else if (gid < 21504) {                // v (transposed out)
        const int r = gid - 17920;
        const int ho = r % 7;
        const int to = (r / 7) & 7;
        const int bh = r / 56;
        pool_task<2, 7, 2, 0>(vin, cwT + 5184, gv, bv, vtout, KPAD, bh, to, ho, 1.f);
    } else {                                 // cls
        const int r = gid - 21504;
        const int tsr = r >> 6, bh = r & 63;
        if (tsr == 0)      pool_cls_v5<0>(qin, gq, bq, qout, QPAD, bh, SCALE_);
        else if (tsr == 1) pool_cls_v5<0>(kin, gk, bk, kout, KPAD, bh, 1.f);
        else               pool_cls_v5<2>(vin, gv, bv, vtout, KPAD, bh, 1.f);
    }
}

// ---------------------------------------------------------------------------
// MFMA attention v3 -> bf16 [M_][768]. 32 q-rows/wave, K reg double-buffer,
// VT hoisted; per-subtile exp/PV interleave (PV0 MFMA overlaps exp1 VALU).
// ---------------------------------------------------------------------------
__global__ __launch_bounds__(256)
void attn_mfma_kernel(const u16* __restrict__ Q, const u16* __restrict__ K,
                      const u16* __restrict__ VT, u16* __restrict__ Out)
{
    __shared__ alignas(16) u16 plds[4][2][512];   // per-wave, per-subtile P tile
    const int tid  = threadIdx.x;
    const int w    = tid >> 6, lane = tid & 63;
    const int c    = lane & 15, g = lane >> 4;

    const unsigned wg = xcd_swizzle(blockIdx.x, gridDim.x);
    const int bh = (int)(wg / 13);
    const int b  = bh >> 3, hh = bh & 7;
    const int q0 = (int)(wg % 13) * 128 + w * 32;

    const size_t qbase = (size_t)bh * QPAD * 96;
    const size_t kbase = (size_t)bh * KPAD * 96;

    short8v qa[2][3];
    #pragma unroll
    for (int s2 = 0; s2 < 2; ++s2)
        #pragma unroll
        for (int kf = 0; kf < 3; ++kf)
            qa[s2][kf] = *(const short8v*)
                &Q[qbase + (size_t)(q0 + s2 * 16 + c) * 96 + kf * 32 + g * 8];

    f32x4 oacc[2][6];
    #pragma unroll
    for (int s2 = 0; s2 < 2; ++s2)
        #pragma unroll
        for (int t = 0; t < 6; ++t) oacc[s2][t] = (f32x4){0.f, 0.f, 0.f, 0.f};
    float lsum[2][4] = {{0.f,0.f,0.f,0.f},{0.f,0.f,0.f,0.f}};

    short8v kb[2][6];
#define LOADK(IDX, PR) do {                                                     \
    _Pragma("unroll")                                                           \
    for (int h = 0; h < 2; ++h)                                                 \
        _Pragma("unroll")                                                       \
        for (int kf = 0; kf < 3; ++kf)                                          \
            kb[IDX][h * 3 + kf] = *(const short8v*)                             \
                &K[kbase + (size_t)((PR) * 32 + h * 16 + c) * 96 + kf * 32 + g * 8]; \
    } while (0)

    LOADK(0, 0);

    #pragma unroll
    for (int pr = 0; pr < 13; ++pr) {
        const int cur = pr & 1, nxt = cur ^ 1;

        short8v vt[6];
        #pragma unroll
        for (int t = 0; t < 6; ++t)
            vt[t] = *(const short8v*)
                &VT[kbase + (size_t)(t * 16 + c) * KPAD + pr * 32 + g * 8];

        f32x4 sacc[2][2];
        __builtin_amdgcn_s_setprio(1);
        #pragma unroll
        for (int s2 = 0; s2 < 2; ++s2)
            #pragma unroll
            for (int h = 0; h < 2; ++h) {
                f32x4 sa = (f32x4){0.f, 0.f, 0.f, 0.f};
                sa = __builtin_amdgcn_mfma_f32_16x16x32_bf16(qa[s2][0], kb[cur][h*3+0], sa, 0, 0, 0);
                sa = __builtin_amdgcn_mfma_f32_16x16x32_bf16(qa[s2][1], kb[cur][h*3+1], sa, 0, 0, 0);
                sa = __builtin_amdgcn_mfma_f32_16x16x32_bf16(qa[s2][2], kb[cur][h*3+2], sa, 0, 0, 0);
                sacc[s2][h] = sa;
            }
        __builtin_amdgcn_s_setprio(0);

        if (pr < 12) LOADK(nxt, pr + 1);

        // subtile 0: exp -> LDS -> PV0 (its MFMA overlaps subtile 1's exp VALU)
        #pragma unroll
        for (int h = 0; h < 2; ++h) {
            const int jcol = pr * 32 + h * 16 + c;
            #pragma unroll
            for (int r = 0; r < 4; ++r) {
                float s = sacc[0][h][r];
                if (jcol >= NKV_) s = -1e30f;
                const float p = __expf(s);
                lsum[0][r] += p;
                const int q    = g * 4 + r;
                const int j    = h * 16 + c;
                const int dstL = q | ((j >> 3) << 4);
                plds[w][0][dstL * 8 + (j & 7)] = f2bf(p);
            }
        }
        asm volatile("s_waitcnt lgkmcnt(0)" ::: "memory");
        __builtin_amdgcn_sched_barrier(0);
        {
            const short8v pa0 = *(const short8v*)&plds[w][0][lane * 8];
            __builtin_amdgcn_s_setprio(1);
            #pragma unroll
            for (int t = 0; t < 6; ++t)
                oacc[0][t] = __builtin_amdgcn_mfma_f32_16x16x32_bf16(pa0, vt[t], oacc[0][t], 0, 0, 0);
            __builtin_amdgcn_s_setprio(0);
        }

        // subtile 1
        #pragma unroll
        for (int h = 0; h < 2; ++h) {
            const int jcol = pr * 32 + h * 16 + c;
            #pragma unroll
            for (int r = 0; r < 4; ++r) {
                float s = sacc[1][h][r];
                if (jcol >= NKV_) s = -1e30f;
                const float p = __expf(s);
                lsum[1][r] += p;
                const int q    = g * 4 + r;
                const int j    = h * 16 + c;
                const int dstL = q | ((j >> 3) << 4);
                plds[w][1][dstL * 8 + (j & 7)] = f2bf(p);
            }
        }
        asm volatile("s_waitcnt lgkmcnt(0)" ::: "memory");
        __builtin_amdgcn_sched_barrier(0);
        {
            const short8v pa1 = *(const short8v*)&plds[w][1][lane * 8];
            __builtin_amdgcn_s_setprio(1);
            #pragma unroll
            for (int t = 0; t < 6; ++t)
                oacc[1][t] = __builtin_amdgcn_mfma_f32_16x16x32_bf16(pa1, vt[t], oacc[1][t], 0, 0, 0);
            __builtin_amdgcn_s_setprio(0);
        }
    }
#undef LOADK

    float linv[2][4];
    #pragma unroll
    for (int s2 = 0; s2 < 2; ++s2)
        #pragma unroll
        for (int r = 0; r < 4; ++r) {
            float s = lsum[s2][r];
            s += __shfl_xor(s, 1, 64);
            s += __shfl_xor(s, 2, 64);
            s += __shfl_xor(s, 4, 64);
            s += __shfl_xor(s, 8, 64);
            linv[s2][r] = 1.f / s;
        }

    #pragma unroll
    for (int s2 = 0; s2 < 2; ++s2)
        #pragma unroll
        for (int t = 0; t < 6; ++t)
            #pragma unroll
            for (int r = 0; r < 4; ++r) {
                const int row = q0 + s2 * 16 + g * 4 + r;
                if (row < N_)
                    Out[((size_t)(b * N_ + row)) * 768 + hh * 96 + t * 16 + c] =
                        f2bf(oacc[s2][t][r] * linv[s2][r]);
            }
}

// ---------------------------------------------------------------------------
extern "C" void kernel_launch(void* const* d_in, const int* in_sizes, int n_in,
                              void* d_out, int out_size, void* d_ws, size_t ws_size,
                              hipStream_t stream)
{
    const float* x     = (const float*)d_in[0];
    const float* Wqkv  = (const float*)d_in[1];
    const float* bqkv  = (const float*)d_in[2];
    const float* Wproj = (const float*)d_in[3];
    const float* bproj = (const float*)d_in[4];
    const float* cwq   = (const float*)d_in[5];
    const float* cwk   = (const float*)d_in[6];
    const float* cwv   = (const float*)d_in[7];
    const float* lnqg  = (const float*)d_in[8];
    const float* lnqb  = (const float*)d_in[9];
    const float* lnkg  = (const float*)d_in[10];
    const float* lnkb  = (const float*)d_in[11];
    const float* lnvg  = (const float*)d_in[12];
    const float* lnvb  = (const float*)d_in[13];

    u16* ws = (u16*)d_ws;
    u16* qkv_raw = ws;                       // 3 x [B][NH][N][D] bf16
    u16* q16 = qkv_raw + 3 * QKV1;           // [64][QPAD][96]
    u16* k16 = q16 + (size_t)64 * QPAD * 96; // [64][KPAD][96]
    u16* vt16 = k16 + (size_t)64 * KPAD * 96;// [64][96][KPAD] (transposed)
    u16* x16    = vt16 + (size_t)64 * KPAD * 96;  // [12552][768]
    u16* Wqkvt  = x16 + (size_t)M_ * 768;         // [2304][768]
    u16* Wprojt = Wqkvt + (size_t)2304 * 768;     // [768][768]
    float* cwT  = (float*)(Wprojt + (size_t)768 * 768);  // 3 x [27][96] f32
    u16* attn16 = qkv_raw;                   // alias: raw dead after pooling
    float* out = (float*)d_out;

    // 0) merged prep: cvt x, transpose weights, transpose conv w, vt pad
    prep_kernel<<<PREP_BLOCKS, 256, 0, stream>>>(
        x, Wqkv, Wproj, cwq, cwk, cwv, x16, Wqkvt, Wprojt, cwT, vt16);

    // 1) qkv GEMM (128x256) with bf16 scatter into q/k/v
    gemm_bf16_kernel<2304, 256, true><<<99 * 9, 512, 0, stream>>>(x16, Wqkvt, bqkv, qkv_raw);

    // 2) pool + LN v5: 16-lane groups, no LDS, task-per-group
    pool_ln_v5_kernel<<<(NTASKS + 15) / 16, 256, 0, stream>>>(
        qkv_raw, qkv_raw + QKV1, qkv_raw + 2 * QKV1, cwT,
        lnqg, lnqb, lnkg, lnkb, lnvg, lnvb, q16, k16, vt16);

    // 3) MFMA attention v3 -> bf16 [M_][768]
    attn_mfma_kernel<<<13 * 64, 256, 0, stream>>>(q16, k16, vt16, attn16);

    // 4) output projection (128x128 -> 594 blocks) -> fp32 d_out
    gemm_bf16_kernel<768, 128, false><<<99 * 6, 512, 0, stream>>>(attn16, Wprojt, bproj, out);
}